// Round 1
// baseline (685.859 us; speedup 1.0000x reference)
//
#include <hip/hip_runtime.h>
#include <math.h>
#include <stdint.h>

#define NB   4
#define NC   1025
#define WSZ  2048
#define STEP 1024
#define FRM  256
#define BAT  32
#define TT   262144

// 2*pi/2048
#define ANG  0.0030679617f
// cos/sin(2*pi/2048)
#define HC1  0.99999529f
#define HS1  0.0030679568f

__device__ __forceinline__ float tanh_fast(float z) {
    float e = __expf(2.0f * z);
    return 1.0f - 2.0f / (e + 1.0f);   // exact tanh identity; inf/0 saturate to +/-1
}

// ---------------- setup: compact nonzero bins per block + softmax(mixer) ----------------
__global__ __launch_bounds__(1024) void setup_kernel(
    const float* __restrict__ transfers, const float* __restrict__ mixer,
    int* __restrict__ counts, int* __restrict__ bins, float* __restrict__ tvals,
    float* __restrict__ wmix, int kmax)
{
    int i = blockIdx.x, tid = threadIdx.x;
    __shared__ int wcnt[16], woff[16];
    float tv = transfers[i * NC + tid];
    bool nz = (tv != 0.0f);
    unsigned long long mask = __ballot(nz);
    int lane = tid & 63, w = tid >> 6;
    int within = __popcll(mask & ((1ULL << lane) - 1ULL));
    if (lane == 0) wcnt[w] = __popcll(mask);
    __syncthreads();
    if (tid == 0) {
        int acc = 0;
        for (int q = 0; q < 16; ++q) { woff[q] = acc; acc += wcnt[q]; }
        float tvL = transfers[i * NC + 1024];       // tail bin k=1024
        if (tvL != 0.0f && acc < kmax) { bins[i * NC + acc] = 1024; tvals[i * NC + acc] = tvL; acc++; }
        counts[i] = (acc < kmax) ? acc : kmax;
        if (i == 0) {                               // softmax of mixer[5]
            float m = mixer[0];
            for (int q = 1; q < 5; ++q) m = fmaxf(m, mixer[q]);
            float e[5], s = 0.f;
            for (int q = 0; q < 5; ++q) { e[q] = __expf(mixer[q] - m); s += e[q]; }
            for (int q = 0; q < 5; ++q) wmix[q] = e[q] / s;
        }
    }
    __syncthreads();
    if (nz) {
        int pos = woff[w] + within;
        if (pos < kmax) { bins[i * NC + pos] = tid; tvals[i * NC + pos] = tv; }
    }
}

// ---------------- analysis: sparse DFT of each frame at the live bins ----------------
// grid = BAT*FRM workgroups of 256 (4 waves); wave w handles bins j = w, w+4, ...
// Each wave holds the full 2048-sample frame in registers (lane holds n = lane + 64*i).
__global__ __launch_bounds__(256) void analysis_kernel(
    const float* __restrict__ x, const int* __restrict__ counts,
    const int* __restrict__ bins, float2* __restrict__ S, int iblk)
{
    int wg = blockIdx.x;
    int b = wg >> 8, f = wg & 255;
    int tid = threadIdx.x;
    int lane = tid & 63, w = tid >> 6;
    int K = counts[iblk];
    const float* xb = x + (size_t)b * TT + (size_t)f * STEP;
    int limit = TT - f * STEP;                 // zero-pad beyond end of signal
    float xr[32];
#pragma unroll
    for (int i = 0; i < 32; ++i) {
        int n = lane + (i << 6);
        xr[i] = (n < limit) ? xb[n] : 0.0f;
    }
    const int* bl = bins + iblk * NC;
    float2* Sout = S + (size_t)(b * FRM + f) * K;
    for (int j = w; j < K; j += 4) {
        int k = bl[j];
        // W = cis(-2*pi*k*64/2048); exact integer phase reduction
        float aW = (float)((k << 6) & 2047) * ANG;
        float sW, cW; __sincosf(aW, &sW, &cW);
        float Wr = cW, Wi = -sW;
        float hr = 0.f, hi = 0.f;                 // Horner: sum_i xr[i] * W^i
#pragma unroll
        for (int i = 31; i >= 0; --i) {
            float nr = hr * Wr - hi * Wi + xr[i];
            hi = hr * Wi + hi * Wr;
            hr = nr;
        }
        // multiply by cis(-2*pi*k*lane/2048)
        float ab = (float)((k * lane) & 2047) * ANG;
        float sb, cb; __sincosf(ab, &sb, &cb);
        float re = hr * cb + hi * sb;
        float im = hi * cb - hr * sb;
#pragma unroll
        for (int m = 32; m >= 1; m >>= 1) {
            re += __shfl_xor(re, m, 64);
            im += __shfl_xor(im, m, 64);
        }
        if (lane == 0) Sout[j] = make_float2(re, im);
    }
}

// ---------------- scan: O_f = (S_f + O_{f-1}) * t_k, in place ----------------
__global__ __launch_bounds__(256) void scan_kernel(
    float2* __restrict__ S, const int* __restrict__ counts,
    const float* __restrict__ tvals, int iblk)
{
    int gid = blockIdx.x * 256 + threadIdx.x;
    int K = counts[iblk];
    int b = gid / NC, j = gid - b * NC;
    if (b >= BAT || j >= K) return;
    float t = tvals[iblk * NC + j];
    float2* Sb = S + (size_t)b * FRM * K;
    float orr = 0.f, oi = 0.f;
    for (int f = 0; f < FRM; ++f) {
        float2 s = Sb[(size_t)f * K + j];
        orr = (s.x + orr) * t;
        oi  = (s.y + oi) * t;
        Sb[(size_t)f * K + j] = make_float2(orr, oi);
    }
}

// ---------------- synthesis: sparse irFFT + hann + overlap-add + tanh + mix ----------------
// grid = BAT*FRM workgroups of 256; wg handles 1024 consecutive samples (4 per thread).
// sample t: f1 = t/1024 (n1 = t%1024, first half), f2 = f1-1 (n2 = n1+1024, second half).
// e^{i2pik*n/2048} = e^{i2pik*t/2048} * (-1)^{k*f};  hann[n1+1024] = 1 - hann[n1].
__global__ __launch_bounds__(256) void synth_kernel(
    const float2* __restrict__ S, const int* __restrict__ counts,
    const int* __restrict__ bins, const float* __restrict__ gains,
    const float* __restrict__ wmix, const float* __restrict__ x,
    float* __restrict__ yout, float* __restrict__ dout, int iblk)
{
    __shared__ float o1r[NC], o1i[NC], o2r[NC], o2i[NC], rdr[NC], rdi[NC];
    __shared__ int   kk[NC];
    int wg = blockIdx.x;
    int b = wg >> 8, seg = wg & 255;
    int tid = threadIdx.x;
    int K = counts[iblk];
    const int* bl = bins + iblk * NC;
    const float2* Ob = S + (size_t)b * FRM * K;
    int f1 = seg, f2 = seg - 1;
    for (int j = tid; j < K; j += 256) {
        int k = bl[j];
        kk[j] = k;
        float g = ((k == 0) || (k == 1024)) ? (1.0f / 2048.0f) : (2.0f / 2048.0f);
        float2 o1 = Ob[(size_t)f1 * K + j];
        float s1 = ((k & f1) & 1) ? -g : g;       // (-1)^(k*f1) * g
        o1r[j] = o1.x * s1; o1i[j] = o1.y * s1;
        float a2r = 0.f, a2i = 0.f;
        if (f2 >= 0) {
            float2 o2 = Ob[(size_t)f2 * K + j];
            float s2 = ((k & f2) & 1) ? -g : g;
            a2r = o2.x * s2; a2i = o2.y * s2;
        }
        o2r[j] = a2r; o2i[j] = a2i;
        float ar = (float)(k & 2047) * ANG;       // per-sample rotation cis(2pik/2048)
        float sr, cr; __sincosf(ar, &sr, &cr);
        rdr[j] = cr; rdi[j] = sr;
    }
    __syncthreads();

    int n1 = tid << 2;
    int t0 = seg * STEP + n1;
    // hann weights for 4 consecutive samples via rotation
    float ah = (float)n1 * ANG;
    float hs, hc; __sincosf(ah, &hs, &hc);
    float hw[4];
    float hcq = hc, hsq = hs;
#pragma unroll
    for (int q = 0; q < 4; ++q) {
        hw[q] = 0.5f - 0.5f * hcq;
        float tmp = hcq * HC1 - hsq * HS1;
        hsq = hcq * HS1 + hsq * HC1;
        hcq = tmp;
    }
    float acc0 = 0.f, acc1 = 0.f, acc2 = 0.f, acc3 = 0.f;
    for (int j = 0; j < K; ++j) {
        int k = kk[j];
        float a0 = (float)((k * t0) & 2047) * ANG;
        float sb, cb; __sincosf(a0, &sb, &cb);
        float R = rdr[j], I = rdi[j];
        float dr = o1r[j] - o2r[j], di = o1i[j] - o2i[j];
        float br = o2r[j], bi = o2i[j];
        {
            float Pr = fmaf(hw[0], dr, br), Pi = fmaf(hw[0], di, bi);
            acc0 += Pr * cb - Pi * sb;
            float tmp = cb * R - sb * I; sb = cb * I + sb * R; cb = tmp;
        }
        {
            float Pr = fmaf(hw[1], dr, br), Pi = fmaf(hw[1], di, bi);
            acc1 += Pr * cb - Pi * sb;
            float tmp = cb * R - sb * I; sb = cb * I + sb * R; cb = tmp;
        }
        {
            float Pr = fmaf(hw[2], dr, br), Pi = fmaf(hw[2], di, bi);
            acc2 += Pr * cb - Pi * sb;
            float tmp = cb * R - sb * I; sb = cb * I + sb * R; cb = tmp;
        }
        {
            float Pr = fmaf(hw[3], dr, br), Pi = fmaf(hw[3], di, bi);
            acc3 += Pr * cb - Pi * sb;
        }
    }
    float gain = gains[iblk];
    float4 yv;
    yv.x = tanh_fast(acc0 * gain);
    yv.y = tanh_fast(acc1 * gain);
    yv.z = tanh_fast(acc2 * gain);
    yv.w = tanh_fast(acc3 * gain);
    size_t base = (size_t)b * TT + (size_t)t0;
    *(float4*)(yout + base) = yv;
    float wn = wmix[iblk + 1];
    float4 dv;
    if (iblk == 0) {
        float4 xv = *(const float4*)(x + base);
        float w0 = wmix[0];
        dv.x = w0 * xv.x + wn * yv.x;
        dv.y = w0 * xv.y + wn * yv.y;
        dv.z = w0 * xv.z + wn * yv.z;
        dv.w = w0 * xv.w + wn * yv.w;
    } else {
        dv = *(const float4*)(dout + base);
        dv.x += wn * yv.x;
        dv.y += wn * yv.y;
        dv.z += wn * yv.z;
        dv.w += wn * yv.w;
    }
    *(float4*)(dout + base) = dv;
}

extern "C" void kernel_launch(void* const* d_in, const int* in_sizes, int n_in,
                              void* d_out, int out_size, void* d_ws, size_t ws_size,
                              hipStream_t stream)
{
    const float* x         = (const float*)d_in[0];
    const float* transfers = (const float*)d_in[1];
    const float* gains     = (const float*)d_in[2];
    const float* mixer     = (const float*)d_in[3];
    float* dout = (float*)d_out;

    uint8_t* ws = (uint8_t*)d_ws;
    int*   counts = (int*)ws;                          // 16 B
    int*   bins   = (int*)(ws + 64);                   // 4*1025*4 = 16400 B
    float* tvals  = (float*)(ws + 64 + 16400);         // 16400 B
    float* wmix   = (float*)(ws + 64 + 16400 + 16400); // 20 B
    const size_t HDR = 65536;
    float2* S = (float2*)(ws + HDR);

    const size_t ybytes = (size_t)BAT * TT * 4;        // 32 MiB per intermediate buffer
    long long avail = (long long)ws_size - (long long)HDR - 2LL * (long long)ybytes;
    long long km = avail / ((long long)BAT * FRM * 8);
    int kmax = (int)((km < 1) ? 1 : ((km > NC) ? NC : km));
    size_t sbytes = (size_t)BAT * FRM * (size_t)kmax * 8;
    float* yA = (float*)(ws + HDR + sbytes);
    float* yB = yA + (size_t)BAT * TT;

    setup_kernel<<<NB, 1024, 0, stream>>>(transfers, mixer, counts, bins, tvals, wmix, kmax);

    const float* yin = x;
    float* youts[4] = { yA, yB, yA, yB };
    for (int i = 0; i < NB; ++i) {
        analysis_kernel<<<BAT * FRM, 256, 0, stream>>>(yin, counts, bins, S, i);
        scan_kernel<<<(BAT * NC + 255) / 256, 256, 0, stream>>>(S, counts, tvals, i);
        synth_kernel<<<BAT * FRM, 256, 0, stream>>>(S, counts, bins, gains, wmix, x,
                                                    youts[i], dout, i);
        yin = youts[i];
    }
}

// Round 2
// 388.639 us; speedup vs baseline: 1.7648x; 1.7648x over previous
//
#include <hip/hip_runtime.h>
#include <math.h>
#include <stdint.h>

#define NB   4
#define NC   1025
#define WSZ  2048
#define STEP 1024
#define FRM  256
#define BAT  32
#define TT   262144

// 2*pi/2048
#define ANG  0.0030679617f
// cos/sin(2*pi/2048)
#define HC1  0.99999529f
#define HS1  0.0030679568f

__device__ __forceinline__ float tanh_fast(float z) {
    float e = __expf(2.0f * z);
    return 1.0f - 2.0f / (e + 1.0f);   // exact tanh identity; inf/0 saturate to +/-1
}

// ---------------- setup: compact nonzero bins per block + softmax(mixer) ----------------
__global__ __launch_bounds__(1024) void setup_kernel(
    const float* __restrict__ transfers, const float* __restrict__ mixer,
    int* __restrict__ counts, int* __restrict__ bins, float* __restrict__ tvals,
    float* __restrict__ wmix, int kmax)
{
    int i = blockIdx.x, tid = threadIdx.x;
    __shared__ int wcnt[16], woff[16];
    float tv = transfers[i * NC + tid];
    bool nz = (tv != 0.0f);
    unsigned long long mask = __ballot(nz);
    int lane = tid & 63, w = tid >> 6;
    int within = __popcll(mask & ((1ULL << lane) - 1ULL));
    if (lane == 0) wcnt[w] = __popcll(mask);
    __syncthreads();
    if (tid == 0) {
        int acc = 0;
        for (int q = 0; q < 16; ++q) { woff[q] = acc; acc += wcnt[q]; }
        float tvL = transfers[i * NC + 1024];       // tail bin k=1024
        if (tvL != 0.0f && acc < kmax) { bins[i * NC + acc] = 1024; tvals[i * NC + acc] = tvL; acc++; }
        counts[i] = (acc < kmax) ? acc : kmax;
        if (i == 0) {                               // softmax of mixer[5]
            float m = mixer[0];
            for (int q = 1; q < 5; ++q) m = fmaxf(m, mixer[q]);
            float e[5], s = 0.f;
            for (int q = 0; q < 5; ++q) { e[q] = __expf(mixer[q] - m); s += e[q]; }
            for (int q = 0; q < 5; ++q) wmix[q] = e[q] / s;
        }
    }
    __syncthreads();
    if (nz) {
        int pos = woff[w] + within;
        if (pos < kmax) { bins[i * NC + pos] = tid; tvals[i * NC + pos] = tv; }
    }
}

// ---------------- analysis: sparse DFT of each 1024-sample HALF-frame ----------------
// Frames overlap 50%: S_{f,k} = H_{f,k} + (-1)^k H_{f+1,k}, H_256 == 0 (pure zero-pad).
// grid = BAT*256 workgroups of 256 (4 waves); wave w handles bins j = w, w+4, ...
// Each wave holds the 1024-sample half-frame in registers (lane holds n = lane + 64*i).
__global__ __launch_bounds__(256) void analysis_kernel(
    const float* __restrict__ x, const int* __restrict__ counts,
    const int* __restrict__ bins, float2* __restrict__ H, int iblk)
{
    int wg = blockIdx.x;
    int b = wg >> 8, h = wg & 255;
    int tid = threadIdx.x;
    int lane = tid & 63, w = tid >> 6;
    int K = counts[iblk];
    const float* xb = x + (size_t)b * TT + (size_t)h * STEP;
    float xr[16];
#pragma unroll
    for (int i = 0; i < 16; ++i) xr[i] = xb[lane + (i << 6)];
    const int* bl = bins + iblk * NC;
    float2* Hout = H + (size_t)(b * FRM + h) * K;
    for (int j = w; j < K; j += 4) {
        int k = bl[j];
        // W = cis(-2*pi*k*64/2048); exact integer phase reduction
        float aW = (float)((k << 6) & 2047) * ANG;
        float sW, cW; __sincosf(aW, &sW, &cW);
        float Wr = cW, Wi = -sW;
        float hr = 0.f, hi = 0.f;                 // Horner: sum_i xr[i] * W^i
#pragma unroll
        for (int i = 15; i >= 0; --i) {
            float nr = hr * Wr - hi * Wi + xr[i];
            hi = hr * Wi + hi * Wr;
            hr = nr;
        }
        // multiply by cis(-2*pi*k*lane/2048)
        float ab = (float)((k * lane) & 2047) * ANG;
        float sb, cb; __sincosf(ab, &sb, &cb);
        float re = hr * cb + hi * sb;
        float im = hi * cb - hr * sb;
#pragma unroll
        for (int m = 32; m >= 1; m >>= 1) {
            re += __shfl_xor(re, m, 64);
            im += __shfl_xor(im, m, 64);
        }
        if (lane == 0) Hout[j] = make_float2(re, im);
    }
}

// ---------------- scan: S_f = H_f + (-1)^k H_{f+1};  O_f = (S_f + O_{f-1}) * t ----------------
// Kogge-Stone over 256 frames; one workgroup per (b, bin). In-place H -> O is race-free:
// every thread's loads complete before the barrier-separated stores.
__global__ __launch_bounds__(256) void scan_kernel(
    float2* __restrict__ S, const int* __restrict__ counts,
    const int* __restrict__ bins, const float* __restrict__ tvals, int iblk)
{
    int K = counts[iblk];
    int wg = blockIdx.x;
    int b = wg & (BAT - 1), j = wg >> 5;
    if (j >= K) return;
    float t = tvals[iblk * NC + j];
    int k = bins[iblk * NC + j];
    int f = threadIdx.x;
    float2* Sb = S + (size_t)b * FRM * K + j;
    float2 h1 = Sb[(size_t)f * K];
    float2 h2 = (f < FRM - 1) ? Sb[(size_t)(f + 1) * K] : make_float2(0.f, 0.f);
    float sgn = (k & 1) ? -1.f : 1.f;
    float ar = (h1.x + sgn * h2.x) * t;
    float ai = (h1.y + sgn * h2.y) * t;
    float g = t;
    __shared__ float shr[FRM], shi[FRM], shg[FRM];
#pragma unroll
    for (int d = 1; d < FRM; d <<= 1) {
        shr[f] = ar; shi[f] = ai; shg[f] = g;
        __syncthreads();
        if (f >= d) {
            ar = fmaf(g, shr[f - d], ar);
            ai = fmaf(g, shi[f - d], ai);
            g *= shg[f - d];
        }
        __syncthreads();
    }
    Sb[(size_t)f * K] = make_float2(ar, ai);
}

// ---------------- synthesis: sparse irFFT + hann + overlap-add + tanh + mix ----------------
// grid = BAT*FRM workgroups of 256; wg handles 1024 consecutive samples (4 per thread).
// sample t: f1 = t/1024 (n1 = t%1024, first half), f2 = f1-1 (n2 = n1+1024, second half).
// e^{i2pik*n/2048} = e^{i2pik*t/2048} * (-1)^{k*f};  hann[n1+1024] = 1 - hann[n1].
__global__ __launch_bounds__(256) void synth_kernel(
    const float2* __restrict__ S, const int* __restrict__ counts,
    const int* __restrict__ bins, const float* __restrict__ gains,
    const float* __restrict__ wmix, const float* __restrict__ x,
    float* __restrict__ yout, float* __restrict__ dout, int iblk)
{
    __shared__ float o1r[NC], o1i[NC], o2r[NC], o2i[NC], rdr[NC], rdi[NC];
    __shared__ int   kk[NC];
    int wg = blockIdx.x;
    int b = wg >> 8, seg = wg & 255;
    int tid = threadIdx.x;
    int K = counts[iblk];
    const int* bl = bins + iblk * NC;
    const float2* Ob = S + (size_t)b * FRM * K;
    int f1 = seg, f2 = seg - 1;
    for (int j = tid; j < K; j += 256) {
        int k = bl[j];
        kk[j] = k;
        float g = ((k == 0) || (k == 1024)) ? (1.0f / 2048.0f) : (2.0f / 2048.0f);
        float2 o1 = Ob[(size_t)f1 * K + j];
        float s1 = ((k & f1) & 1) ? -g : g;       // (-1)^(k*f1) * g
        o1r[j] = o1.x * s1; o1i[j] = o1.y * s1;
        float a2r = 0.f, a2i = 0.f;
        if (f2 >= 0) {
            float2 o2 = Ob[(size_t)f2 * K + j];
            float s2 = ((k & f2) & 1) ? -g : g;
            a2r = o2.x * s2; a2i = o2.y * s2;
        }
        o2r[j] = a2r; o2i[j] = a2i;
        float ar = (float)(k & 2047) * ANG;       // per-sample rotation cis(2pik/2048)
        float sr, cr; __sincosf(ar, &sr, &cr);
        rdr[j] = cr; rdi[j] = sr;
    }
    __syncthreads();

    int n1 = tid << 2;
    int t0 = seg * STEP + n1;
    // hann weights for 4 consecutive samples via rotation
    float ah = (float)n1 * ANG;
    float hs, hc; __sincosf(ah, &hs, &hc);
    float hw[4];
    float hcq = hc, hsq = hs;
#pragma unroll
    for (int q = 0; q < 4; ++q) {
        hw[q] = 0.5f - 0.5f * hcq;
        float tmp = hcq * HC1 - hsq * HS1;
        hsq = hcq * HS1 + hsq * HC1;
        hcq = tmp;
    }
    float acc0 = 0.f, acc1 = 0.f, acc2 = 0.f, acc3 = 0.f;
    for (int j = 0; j < K; ++j) {
        int k = kk[j];
        float a0 = (float)((k * t0) & 2047) * ANG;
        float sb, cb; __sincosf(a0, &sb, &cb);
        float R = rdr[j], I = rdi[j];
        float dr = o1r[j] - o2r[j], di = o1i[j] - o2i[j];
        float br = o2r[j], bi = o2i[j];
        {
            float Pr = fmaf(hw[0], dr, br), Pi = fmaf(hw[0], di, bi);
            acc0 += Pr * cb - Pi * sb;
            float tmp = cb * R - sb * I; sb = cb * I + sb * R; cb = tmp;
        }
        {
            float Pr = fmaf(hw[1], dr, br), Pi = fmaf(hw[1], di, bi);
            acc1 += Pr * cb - Pi * sb;
            float tmp = cb * R - sb * I; sb = cb * I + sb * R; cb = tmp;
        }
        {
            float Pr = fmaf(hw[2], dr, br), Pi = fmaf(hw[2], di, bi);
            acc2 += Pr * cb - Pi * sb;
            float tmp = cb * R - sb * I; sb = cb * I + sb * R; cb = tmp;
        }
        {
            float Pr = fmaf(hw[3], dr, br), Pi = fmaf(hw[3], di, bi);
            acc3 += Pr * cb - Pi * sb;
        }
    }
    float gain = gains[iblk];
    float4 yv;
    yv.x = tanh_fast(acc0 * gain);
    yv.y = tanh_fast(acc1 * gain);
    yv.z = tanh_fast(acc2 * gain);
    yv.w = tanh_fast(acc3 * gain);
    size_t base = (size_t)b * TT + (size_t)t0;
    *(float4*)(yout + base) = yv;
    float wn = wmix[iblk + 1];
    float4 dv;
    if (iblk == 0) {
        float4 xv = *(const float4*)(x + base);
        float w0 = wmix[0];
        dv.x = w0 * xv.x + wn * yv.x;
        dv.y = w0 * xv.y + wn * yv.y;
        dv.z = w0 * xv.z + wn * yv.z;
        dv.w = w0 * xv.w + wn * yv.w;
    } else {
        dv = *(const float4*)(dout + base);
        dv.x += wn * yv.x;
        dv.y += wn * yv.y;
        dv.z += wn * yv.z;
        dv.w += wn * yv.w;
    }
    *(float4*)(dout + base) = dv;
}

extern "C" void kernel_launch(void* const* d_in, const int* in_sizes, int n_in,
                              void* d_out, int out_size, void* d_ws, size_t ws_size,
                              hipStream_t stream)
{
    const float* x         = (const float*)d_in[0];
    const float* transfers = (const float*)d_in[1];
    const float* gains     = (const float*)d_in[2];
    const float* mixer     = (const float*)d_in[3];
    float* dout = (float*)d_out;

    uint8_t* ws = (uint8_t*)d_ws;
    int*   counts = (int*)ws;                          // 16 B
    int*   bins   = (int*)(ws + 64);                   // 4*1025*4 = 16400 B
    float* tvals  = (float*)(ws + 64 + 16400);         // 16400 B
    float* wmix   = (float*)(ws + 64 + 16400 + 16400); // 20 B
    const size_t HDR = 65536;
    float2* S = (float2*)(ws + HDR);

    const size_t ybytes = (size_t)BAT * TT * 4;        // 32 MiB per intermediate buffer
    long long avail = (long long)ws_size - (long long)HDR - 2LL * (long long)ybytes;
    long long km = avail / ((long long)BAT * FRM * 8);
    int kmax = (int)((km < 1) ? 1 : ((km > NC) ? NC : km));
    size_t sbytes = (size_t)BAT * FRM * (size_t)kmax * 8;
    float* yA = (float*)(ws + HDR + sbytes);
    float* yB = yA + (size_t)BAT * TT;

    setup_kernel<<<NB, 1024, 0, stream>>>(transfers, mixer, counts, bins, tvals, wmix, kmax);

    const float* yin = x;
    float* youts[4] = { yA, yB, yA, yB };
    for (int i = 0; i < NB; ++i) {
        analysis_kernel<<<BAT * FRM, 256, 0, stream>>>(yin, counts, bins, S, i);
        scan_kernel<<<BAT * NC, 256, 0, stream>>>(S, counts, bins, tvals, i);
        synth_kernel<<<BAT * FRM, 256, 0, stream>>>(S, counts, bins, gains, wmix, x,
                                                    youts[i], dout, i);
        yin = youts[i];
    }
}

// Round 3
// 379.228 us; speedup vs baseline: 1.8086x; 1.0248x over previous
//
#include <hip/hip_runtime.h>
#include <math.h>
#include <stdint.h>

#define NB   4
#define NC   1025
#define WSZ  2048
#define STEP 1024
#define FRM  256
#define BAT  32
#define TT   262144
#define KC   128     // bin chunk held in LDS by the synth kernel

// 2*pi/2048
#define ANG  0.0030679617f
// cos/sin(2*pi/2048)
#define HC1  0.99999529f
#define HS1  0.0030679568f

__device__ __forceinline__ float tanh_fast(float z) {
    float e = __expf(2.0f * z);
    return 1.0f - 2.0f / (e + 1.0f);   // exact tanh identity; inf/0 saturate to +/-1
}

// ---------------- setup: compact nonzero bins per block + softmax(mixer) ----------------
__global__ __launch_bounds__(1024) void setup_kernel(
    const float* __restrict__ transfers, const float* __restrict__ mixer,
    int* __restrict__ counts, int* __restrict__ bins, float* __restrict__ tvals,
    float* __restrict__ wmix, int kmax)
{
    int i = blockIdx.x, tid = threadIdx.x;
    __shared__ int wcnt[16], woff[16];
    float tv = transfers[i * NC + tid];
    bool nz = (tv != 0.0f);
    unsigned long long mask = __ballot(nz);
    int lane = tid & 63, w = tid >> 6;
    int within = __popcll(mask & ((1ULL << lane) - 1ULL));
    if (lane == 0) wcnt[w] = __popcll(mask);
    __syncthreads();
    if (tid == 0) {
        int acc = 0;
        for (int q = 0; q < 16; ++q) { woff[q] = acc; acc += wcnt[q]; }
        float tvL = transfers[i * NC + 1024];       // tail bin k=1024
        if (tvL != 0.0f && acc < kmax) { bins[i * NC + acc] = 1024; tvals[i * NC + acc] = tvL; acc++; }
        counts[i] = (acc < kmax) ? acc : kmax;
        if (i == 0) {                               // softmax of mixer[5]
            float m = mixer[0];
            for (int q = 1; q < 5; ++q) m = fmaxf(m, mixer[q]);
            float e[5], s = 0.f;
            for (int q = 0; q < 5; ++q) { e[q] = __expf(mixer[q] - m); s += e[q]; }
            for (int q = 0; q < 5; ++q) wmix[q] = e[q] / s;
        }
    }
    __syncthreads();
    if (nz) {
        int pos = woff[w] + within;
        if (pos < kmax) { bins[i * NC + pos] = tid; tvals[i * NC + pos] = tv; }
    }
}

// ---------------- analysis (block 0 only): sparse DFT of each 1024-sample half-frame ----------------
// S_{f,k} = H_{f,k} + (-1)^k H_{f+1,k}, H_256 == 0 (pure zero-pad); combine happens in scan.
__global__ __launch_bounds__(256) void analysis_kernel(
    const float* __restrict__ x, const int* __restrict__ counts,
    const int* __restrict__ bins, float2* __restrict__ H, int iblk)
{
    int wg = blockIdx.x;
    int b = wg >> 8, h = wg & 255;
    int tid = threadIdx.x;
    int lane = tid & 63, w = tid >> 6;
    int K = counts[iblk];
    const float* xb = x + (size_t)b * TT + (size_t)h * STEP;
    float xr[16];
#pragma unroll
    for (int i = 0; i < 16; ++i) xr[i] = xb[lane + (i << 6)];
    const int* bl = bins + iblk * NC;
    float2* Hout = H + (size_t)(b * FRM + h) * K;
    for (int j = w; j < K; j += 4) {
        int k = bl[j];
        float aW = (float)((k << 6) & 2047) * ANG;     // W = cis(-2pi*k*64/2048)
        float sW, cW; __sincosf(aW, &sW, &cW);
        float Wr = cW, Wi = -sW;
        float hr = 0.f, hi = 0.f;                      // Horner: sum_i xr[i] * W^i
#pragma unroll
        for (int i = 15; i >= 0; --i) {
            float nr = hr * Wr - hi * Wi + xr[i];
            hi = hr * Wi + hi * Wr;
            hr = nr;
        }
        float ab = (float)((k * lane) & 2047) * ANG;   // * cis(-2pi*k*lane/2048)
        float sb, cb; __sincosf(ab, &sb, &cb);
        float re = hr * cb + hi * sb;
        float im = hi * cb - hr * sb;
#pragma unroll
        for (int m = 32; m >= 1; m >>= 1) {
            re += __shfl_xor(re, m, 64);
            im += __shfl_xor(im, m, 64);
        }
        if (lane == 0) Hout[j] = make_float2(re, im);
    }
}

// ---------------- scan: S_f = H_f + (-1)^k H_{f+1};  O_f = (S_f + O_{f-1}) * t ----------------
// Kogge-Stone over 256 frames; one workgroup per (b, bin). In-place H -> O is race-free:
// every thread's loads complete before the barrier-separated stores.
__global__ __launch_bounds__(256) void scan_kernel(
    float2* __restrict__ S, const int* __restrict__ counts,
    const int* __restrict__ bins, const float* __restrict__ tvals, int iblk)
{
    int K = counts[iblk];
    int wg = blockIdx.x;
    int b = wg & (BAT - 1), j = wg >> 5;
    if (j >= K) return;
    float t = tvals[iblk * NC + j];
    int k = bins[iblk * NC + j];
    int f = threadIdx.x;
    float2* Sb = S + (size_t)b * FRM * K + j;
    float2 h1 = Sb[(size_t)f * K];
    float2 h2 = (f < FRM - 1) ? Sb[(size_t)(f + 1) * K] : make_float2(0.f, 0.f);
    float sgn = (k & 1) ? -1.f : 1.f;
    float ar = (h1.x + sgn * h2.x) * t;
    float ai = (h1.y + sgn * h2.y) * t;
    float g = t;
    __shared__ float shr[FRM], shi[FRM], shg[FRM];
#pragma unroll
    for (int d = 1; d < FRM; d <<= 1) {
        shr[f] = ar; shi[f] = ai; shg[f] = g;
        __syncthreads();
        if (f >= d) {
            ar = fmaf(g, shr[f - d], ar);
            ai = fmaf(g, shi[f - d], ai);
            g *= shg[f - d];
        }
        __syncthreads();
    }
    Sb[(size_t)f * K] = make_float2(ar, ai);
}

// ---------------- fused synthesis + next-block analysis ----------------
// grid = BAT*FRM workgroups of 256; wg (b,seg) produces samples [seg*1024,(seg+1)*1024).
// In-frame phase: sample t = seg*1024+n1 gets hw*Re[c1 e^{i 2pi k n1/2048}] +
// (1-hw)*Re[c2' e^{i 2pi k n1/2048}] where c1 = g*O_{f1}, c2' = g*(-1)^k*O_{f2}.
// hw is k-independent -> accumulate A = sum Re[c2' e], B = sum Re[(c1-c2') e]; out = A + hw*B.
// Then the 1024 samples (= half-frame h=seg of y) are staged through LDS and the
// next block's half-frame DFT H_{i+1} is computed in the same workgroup (y never hits HBM).
__global__ __launch_bounds__(256) void fused_synth_kernel(
    const float2* __restrict__ S, float2* __restrict__ H2,
    const int* __restrict__ counts, const int* __restrict__ bins,
    const float* __restrict__ gains, const float* __restrict__ wmix,
    const float* __restrict__ x, float* __restrict__ dout,
    int iblk, int do_an)
{
    __shared__ float4 cdat[KC];     // c2r, c2i, c1r-c2r, c1i-c2i
    __shared__ float2 rot[KC];      // cis(2pi k/2048)
    __shared__ int    kks[KC];
    __shared__ float4 ystage4[256];

    int wg = blockIdx.x;
    int b = wg >> 8, seg = wg & 255;
    int tid = threadIdx.x;
    int K = counts[iblk];
    const int* bl = bins + iblk * NC;
    const float2* Ob = S + (size_t)b * FRM * K;
    int f1 = seg, f2 = seg - 1;
    int n1 = tid << 2;

    float accA0 = 0.f, accA1 = 0.f, accA2 = 0.f, accA3 = 0.f;
    float accB0 = 0.f, accB1 = 0.f, accB2 = 0.f, accB3 = 0.f;

    for (int c0 = 0; c0 < K; c0 += KC) {
        int cs = (K - c0 < KC) ? (K - c0) : KC;
        if (tid < cs) {
            int j = c0 + tid;
            int k = bl[j];
            float g = ((k == 0) || (k == 1024)) ? (1.0f / 2048.0f) : (2.0f / 2048.0f);
            float2 o1 = Ob[(size_t)f1 * K + j];
            float c1r = o1.x * g, c1i = o1.y * g;
            float c2r = 0.f, c2i = 0.f;
            if (f2 >= 0) {
                float2 o2 = Ob[(size_t)f2 * K + j];
                float s = (k & 1) ? -g : g;            // fold (-1)^k into second half
                c2r = o2.x * s; c2i = o2.y * s;
            }
            cdat[tid] = make_float4(c2r, c2i, c1r - c2r, c1i - c2i);
            float ar = (float)(k & 2047) * ANG;
            float sr, cr; __sincosf(ar, &sr, &cr);
            rot[tid] = make_float2(cr, sr);
            kks[tid] = k;
        }
        __syncthreads();
        for (int jj = 0; jj < cs; ++jj) {
            int k = kks[jj];
            float4 cd = cdat[jj];
            float2 ri = rot[jj];
            float a0 = (float)((k * n1) & 2047) * ANG;
            float sb, cb; __sincosf(a0, &sb, &cb);
            accA0 = fmaf(cd.x, cb, accA0); accA0 = fmaf(-cd.y, sb, accA0);
            accB0 = fmaf(cd.z, cb, accB0); accB0 = fmaf(-cd.w, sb, accB0);
            { float tmp = cb * ri.x - sb * ri.y; sb = sb * ri.x + cb * ri.y; cb = tmp; }
            accA1 = fmaf(cd.x, cb, accA1); accA1 = fmaf(-cd.y, sb, accA1);
            accB1 = fmaf(cd.z, cb, accB1); accB1 = fmaf(-cd.w, sb, accB1);
            { float tmp = cb * ri.x - sb * ri.y; sb = sb * ri.x + cb * ri.y; cb = tmp; }
            accA2 = fmaf(cd.x, cb, accA2); accA2 = fmaf(-cd.y, sb, accA2);
            accB2 = fmaf(cd.z, cb, accB2); accB2 = fmaf(-cd.w, sb, accB2);
            { float tmp = cb * ri.x - sb * ri.y; sb = sb * ri.x + cb * ri.y; cb = tmp; }
            accA3 = fmaf(cd.x, cb, accA3); accA3 = fmaf(-cd.y, sb, accA3);
            accB3 = fmaf(cd.z, cb, accB3); accB3 = fmaf(-cd.w, sb, accB3);
        }
        __syncthreads();
    }

    // hann weights for the 4 samples via rotation
    float ah = (float)n1 * ANG;
    float hs, hc; __sincosf(ah, &hs, &hc);
    float hw0, hw1, hw2, hw3;
    {
        float hcq = hc, hsq = hs;
        hw0 = 0.5f - 0.5f * hcq;
        { float t0 = hcq * HC1 - hsq * HS1; hsq = hcq * HS1 + hsq * HC1; hcq = t0; }
        hw1 = 0.5f - 0.5f * hcq;
        { float t0 = hcq * HC1 - hsq * HS1; hsq = hcq * HS1 + hsq * HC1; hcq = t0; }
        hw2 = 0.5f - 0.5f * hcq;
        { float t0 = hcq * HC1 - hsq * HS1; hsq = hcq * HS1 + hsq * HC1; hcq = t0; }
        hw3 = 0.5f - 0.5f * hcq;
    }
    float gain = gains[iblk];
    float4 yv;
    yv.x = tanh_fast((accA0 + hw0 * accB0) * gain);
    yv.y = tanh_fast((accA1 + hw1 * accB1) * gain);
    yv.z = tanh_fast((accA2 + hw2 * accB2) * gain);
    yv.w = tanh_fast((accA3 + hw3 * accB3) * gain);

    size_t base = (size_t)b * TT + (size_t)seg * STEP + (size_t)n1;
    float wn = wmix[iblk + 1];
    float4 dv;
    if (iblk == 0) {
        float4 xv = *(const float4*)(x + base);
        float w0 = wmix[0];
        dv.x = w0 * xv.x + wn * yv.x;
        dv.y = w0 * xv.y + wn * yv.y;
        dv.z = w0 * xv.z + wn * yv.z;
        dv.w = w0 * xv.w + wn * yv.w;
    } else {
        dv = *(const float4*)(dout + base);
        dv.x += wn * yv.x;
        dv.y += wn * yv.y;
        dv.z += wn * yv.z;
        dv.w += wn * yv.w;
    }
    *(float4*)(dout + base) = dv;

    if (do_an) {
        ystage4[tid] = yv;
        __syncthreads();
        int K2 = counts[iblk + 1];
        if (K2 > 0) {
            const float* ys = (const float*)ystage4;
            int lane = tid & 63, w = tid >> 6;
            float xr[16];
#pragma unroll
            for (int i = 0; i < 16; ++i) xr[i] = ys[lane + (i << 6)];
            const int* bl2 = bins + (iblk + 1) * NC;
            float2* Hout = H2 + (size_t)(b * FRM + seg) * K2;
            for (int j = w; j < K2; j += 4) {
                int k = bl2[j];
                float aW = (float)((k << 6) & 2047) * ANG;
                float sW, cW; __sincosf(aW, &sW, &cW);
                float Wr = cW, Wi = -sW;
                float hr = 0.f, hi = 0.f;
#pragma unroll
                for (int i = 15; i >= 0; --i) {
                    float nr = hr * Wr - hi * Wi + xr[i];
                    hi = hr * Wi + hi * Wr;
                    hr = nr;
                }
                float ab = (float)((k * lane) & 2047) * ANG;
                float sb, cb; __sincosf(ab, &sb, &cb);
                float re = hr * cb + hi * sb;
                float im = hi * cb - hr * sb;
#pragma unroll
                for (int m = 32; m >= 1; m >>= 1) {
                    re += __shfl_xor(re, m, 64);
                    im += __shfl_xor(im, m, 64);
                }
                if (lane == 0) Hout[j] = make_float2(re, im);
            }
        }
    }
}

extern "C" void kernel_launch(void* const* d_in, const int* in_sizes, int n_in,
                              void* d_out, int out_size, void* d_ws, size_t ws_size,
                              hipStream_t stream)
{
    const float* x         = (const float*)d_in[0];
    const float* transfers = (const float*)d_in[1];
    const float* gains     = (const float*)d_in[2];
    const float* mixer     = (const float*)d_in[3];
    float* dout = (float*)d_out;

    uint8_t* ws = (uint8_t*)d_ws;
    int*   counts = (int*)ws;                          // 16 B
    int*   bins   = (int*)(ws + 64);                   // 4*1025*4 = 16400 B
    float* tvals  = (float*)(ws + 64 + 16400);         // 16400 B
    float* wmix   = (float*)(ws + 64 + 16400 + 16400); // 20 B
    const size_t HDR = 65536;

    // two ping-pong spectral buffers (y intermediates never touch HBM anymore)
    long long km = ((long long)ws_size - (long long)HDR) / (2LL * BAT * FRM * 8);
    int kmax = (int)((km < 1) ? 1 : ((km > NC) ? NC : km));
    float2* S0 = (float2*)(ws + HDR);
    float2* S1 = S0 + (size_t)BAT * FRM * kmax;

    setup_kernel<<<NB, 1024, 0, stream>>>(transfers, mixer, counts, bins, tvals, wmix, kmax);
    analysis_kernel<<<BAT * FRM, 256, 0, stream>>>(x, counts, bins, S0, 0);

    float2* cur = S0;
    float2* nxt = S1;
    for (int i = 0; i < NB; ++i) {
        scan_kernel<<<BAT * NC, 256, 0, stream>>>(cur, counts, bins, tvals, i);
        fused_synth_kernel<<<BAT * FRM, 256, 0, stream>>>(cur, nxt, counts, bins, gains,
                                                          wmix, x, dout, i, (i < NB - 1) ? 1 : 0);
        float2* t = cur; cur = nxt; nxt = t;
    }
}

// Round 4
// 332.579 us; speedup vs baseline: 2.0622x; 1.1403x over previous
//
#include <hip/hip_runtime.h>
#include <math.h>
#include <stdint.h>

#define NB   4
#define NC   1025
#define WSZ  2048
#define STEP 1024
#define FRM  256
#define BAT  32
#define TT   262144
#define KC   128     // bin chunk held in LDS by the synth kernel

// 1/2048 (exact): phases are integers mod 2048 -> revolutions for v_sin/v_cos
#define RREV (1.0f / 2048.0f)

__device__ __forceinline__ float tanh_fast(float z) {
    float e = __expf(2.0f * z);
    return 1.0f - 2.0f / (e + 1.0f);   // exact tanh identity; inf/0 saturate to +/-1
}

// hardware cis: idx taken mod 2048, argument in revolutions (exact, no range reduction)
__device__ __forceinline__ void cis_rev(int idx, float* c, float* s) {
    float rev = (float)(idx & 2047) * RREV;
    *c = __builtin_amdgcn_cosf(rev);
    *s = __builtin_amdgcn_sinf(rev);
}

// ---------------- setup: compact nonzero bins per block + softmax(mixer) ----------------
__global__ __launch_bounds__(1024) void setup_kernel(
    const float* __restrict__ transfers, const float* __restrict__ mixer,
    int* __restrict__ counts, int* __restrict__ bins, float* __restrict__ tvals,
    float* __restrict__ wmix, int kmax)
{
    int i = blockIdx.x, tid = threadIdx.x;
    __shared__ int wcnt[16], woff[16];
    float tv = transfers[i * NC + tid];
    bool nz = (tv != 0.0f);
    unsigned long long mask = __ballot(nz);
    int lane = tid & 63, w = tid >> 6;
    int within = __popcll(mask & ((1ULL << lane) - 1ULL));
    if (lane == 0) wcnt[w] = __popcll(mask);
    __syncthreads();
    if (tid == 0) {
        int acc = 0;
        for (int q = 0; q < 16; ++q) { woff[q] = acc; acc += wcnt[q]; }
        float tvL = transfers[i * NC + 1024];       // tail bin k=1024
        if (tvL != 0.0f && acc < kmax) { bins[i * NC + acc] = 1024; tvals[i * NC + acc] = tvL; acc++; }
        counts[i] = (acc < kmax) ? acc : kmax;
        if (i == 0) {                               // softmax of mixer[5]
            float m = mixer[0];
            for (int q = 1; q < 5; ++q) m = fmaxf(m, mixer[q]);
            float e[5], s = 0.f;
            for (int q = 0; q < 5; ++q) { e[q] = __expf(mixer[q] - m); s += e[q]; }
            for (int q = 0; q < 5; ++q) wmix[q] = e[q] / s;
        }
    }
    __syncthreads();
    if (nz) {
        int pos = woff[w] + within;
        if (pos < kmax) { bins[i * NC + pos] = tid; tvals[i * NC + pos] = tv; }
    }
}

// ---------------- twiddle tables: T[i][j][n] = cis(2pi k_j n / 2048), n in [0,1024) ----------------
__global__ __launch_bounds__(256) void twiddle_kernel(
    const int* __restrict__ counts, const int* __restrict__ bins,
    float2* __restrict__ TW, int kmax)
{
    int i = blockIdx.x >> 5, c = blockIdx.x & 31;
    int K = counts[i];
    for (int j = c; j < K; j += 32) {
        int k = bins[i * NC + j];
        float2* row = TW + ((size_t)i * kmax + j) * 1024;
        for (int n = threadIdx.x; n < 1024; n += 256) {
            float cc, ss; cis_rev(k * n, &cc, &ss);
            row[n] = make_float2(cc, ss);
        }
    }
}

// ---------------- analysis (block 0 only): sparse DFT of each 1024-sample half-frame ----------------
// S_{f,k} = H_{f,k} + (-1)^k H_{f+1,k}, H_256 == 0 (pure zero-pad); combine happens in scan.
__global__ __launch_bounds__(256) void analysis_kernel(
    const float* __restrict__ x, const int* __restrict__ counts,
    const int* __restrict__ bins, float2* __restrict__ H, int iblk)
{
    int wg = blockIdx.x;
    int b = wg >> 8, h = wg & 255;
    int tid = threadIdx.x;
    int lane = tid & 63, w = tid >> 6;
    int K = counts[iblk];
    const float* xb = x + (size_t)b * TT + (size_t)h * STEP;
    float xr[16];
#pragma unroll
    for (int i = 0; i < 16; ++i) xr[i] = xb[lane + (i << 6)];
    const int* bl = bins + iblk * NC;
    float2* Hout = H + (size_t)(b * FRM + h) * K;
    for (int j = w; j < K; j += 4) {
        int k = bl[j];
        float cW, sW; cis_rev(k << 6, &cW, &sW);   // W = cis(-2pi*k*64/2048)
        float Wr = cW, Wi = -sW;
        float hr = 0.f, hi = 0.f;                  // Horner: sum_i xr[i] * W^i
#pragma unroll
        for (int i = 15; i >= 0; --i) {
            float nr = hr * Wr - hi * Wi + xr[i];
            hi = hr * Wi + hi * Wr;
            hr = nr;
        }
        float cb, sb; cis_rev(k * lane, &cb, &sb); // * cis(-2pi*k*lane/2048)
        float re = hr * cb + hi * sb;
        float im = hi * cb - hr * sb;
#pragma unroll
        for (int m = 32; m >= 1; m >>= 1) {
            re += __shfl_xor(re, m, 64);
            im += __shfl_xor(im, m, 64);
        }
        if (lane == 0) Hout[j] = make_float2(re, im);
    }
}

// ---------------- scan: S_f = H_f + (-1)^k H_{f+1};  O_f = (S_f + O_{f-1}) * t ----------------
// Kogge-Stone over 256 frames; grid = BAT*64 wgs, wg (b, j0) loops bins j = j0, j0+64, ...
// Loop/barriers are uniform within a workgroup (K is wg-independent). In-place is race-free.
__global__ __launch_bounds__(256) void scan_kernel(
    float2* __restrict__ S, const int* __restrict__ counts,
    const int* __restrict__ bins, const float* __restrict__ tvals, int iblk)
{
    int K = counts[iblk];
    int wg = blockIdx.x;
    int b = wg & (BAT - 1), j0 = wg >> 5;
    int f = threadIdx.x;
    __shared__ float shr[FRM], shi[FRM], shg[FRM];
    for (int j = j0; j < K; j += 64) {
        float t = tvals[iblk * NC + j];
        int k = bins[iblk * NC + j];
        float2* Sb = S + (size_t)b * FRM * K + j;
        float2 h1 = Sb[(size_t)f * K];
        float2 h2 = (f < FRM - 1) ? Sb[(size_t)(f + 1) * K] : make_float2(0.f, 0.f);
        float sgn = (k & 1) ? -1.f : 1.f;
        float ar = (h1.x + sgn * h2.x) * t;
        float ai = (h1.y + sgn * h2.y) * t;
        float g = t;
#pragma unroll
        for (int d = 1; d < FRM; d <<= 1) {
            shr[f] = ar; shi[f] = ai; shg[f] = g;
            __syncthreads();
            if (f >= d) {
                ar = fmaf(g, shr[f - d], ar);
                ai = fmaf(g, shi[f - d], ai);
                g *= shg[f - d];
            }
            __syncthreads();
        }
        Sb[(size_t)f * K] = make_float2(ar, ai);
        __syncthreads();
    }
}

// ---------------- fused synthesis + next-block analysis ----------------
// grid = BAT*FRM workgroups of 256; wg (b,seg) produces samples [seg*1024,(seg+1)*1024).
// out[n1] = A + hann[n1]*B with A = sum Re[c2' e^{i 2pi k n1/2048}], B = sum Re[(c1-c2') e],
// c1 = g*O_{f1}, c2' = g*(-1)^k*O_{f2}; e comes from the precomputed L2-resident table.
// The 1024 produced samples (= half-frame seg of y) are staged through LDS and the next
// block's half-frame DFT is computed in the same workgroup (y never touches HBM).
__global__ __launch_bounds__(256) void fused_synth_kernel(
    const float2* __restrict__ S, float2* __restrict__ H2,
    const float2* __restrict__ TW,
    const int* __restrict__ counts, const int* __restrict__ bins,
    const float* __restrict__ gains, const float* __restrict__ wmix,
    const float* __restrict__ x, float* __restrict__ dout,
    int iblk, int do_an, int kmax)
{
    __shared__ float4 cdat[KC];     // c2r, c2i, c1r-c2r, c1i-c2i
    __shared__ float4 ystage4[256];

    int wg = blockIdx.x;
    int b = wg >> 8, seg = wg & 255;
    int tid = threadIdx.x;
    int K = counts[iblk];
    const int* bl = bins + iblk * NC;
    const float2* Ob = S + (size_t)b * FRM * K;
    const float2* TWb = TW + (size_t)iblk * kmax * 1024;
    int f1 = seg, f2 = seg - 1;
    int n1 = tid << 2;

    float accA0 = 0.f, accA1 = 0.f, accA2 = 0.f, accA3 = 0.f;
    float accB0 = 0.f, accB1 = 0.f, accB2 = 0.f, accB3 = 0.f;

    for (int c0 = 0; c0 < K; c0 += KC) {
        int cs = (K - c0 < KC) ? (K - c0) : KC;
        if (tid < cs) {
            int j = c0 + tid;
            int k = bl[j];
            float g = ((k == 0) || (k == 1024)) ? (1.0f / 2048.0f) : (2.0f / 2048.0f);
            float2 o1 = Ob[(size_t)f1 * K + j];
            float c1r = o1.x * g, c1i = o1.y * g;
            float c2r = 0.f, c2i = 0.f;
            if (f2 >= 0) {
                float2 o2 = Ob[(size_t)f2 * K + j];
                float s = (k & 1) ? -g : g;            // fold (-1)^k into second half
                c2r = o2.x * s; c2i = o2.y * s;
            }
            cdat[tid] = make_float4(c2r, c2i, c1r - c2r, c1i - c2i);
        }
        __syncthreads();
        for (int jj = 0; jj < cs; ++jj) {
            float4 cd = cdat[jj];
            const float4* tp = (const float4*)(TWb + (size_t)(c0 + jj) * 1024 + n1);
            float4 tA = tp[0];   // c0,s0,c1,s1
            float4 tB = tp[1];   // c2,s2,c3,s3
            accA0 = fmaf(cd.x, tA.x, accA0); accA0 = fmaf(-cd.y, tA.y, accA0);
            accB0 = fmaf(cd.z, tA.x, accB0); accB0 = fmaf(-cd.w, tA.y, accB0);
            accA1 = fmaf(cd.x, tA.z, accA1); accA1 = fmaf(-cd.y, tA.w, accA1);
            accB1 = fmaf(cd.z, tA.z, accB1); accB1 = fmaf(-cd.w, tA.w, accB1);
            accA2 = fmaf(cd.x, tB.x, accA2); accA2 = fmaf(-cd.y, tB.y, accA2);
            accB2 = fmaf(cd.z, tB.x, accB2); accB2 = fmaf(-cd.w, tB.y, accB2);
            accA3 = fmaf(cd.x, tB.z, accA3); accA3 = fmaf(-cd.y, tB.w, accA3);
            accB3 = fmaf(cd.z, tB.z, accB3); accB3 = fmaf(-cd.w, tB.w, accB3);
        }
        __syncthreads();
    }

    // hann weights for the 4 samples: 0.5 - 0.5*cos(2pi n/2048), n in [0,1024)
    float hw0, hw1, hw2, hw3;
    {
        float c0_, s0_;
        cis_rev(n1 + 0, &c0_, &s0_); hw0 = 0.5f - 0.5f * c0_;
        cis_rev(n1 + 1, &c0_, &s0_); hw1 = 0.5f - 0.5f * c0_;
        cis_rev(n1 + 2, &c0_, &s0_); hw2 = 0.5f - 0.5f * c0_;
        cis_rev(n1 + 3, &c0_, &s0_); hw3 = 0.5f - 0.5f * c0_;
    }
    float gain = gains[iblk];
    float4 yv;
    yv.x = tanh_fast((accA0 + hw0 * accB0) * gain);
    yv.y = tanh_fast((accA1 + hw1 * accB1) * gain);
    yv.z = tanh_fast((accA2 + hw2 * accB2) * gain);
    yv.w = tanh_fast((accA3 + hw3 * accB3) * gain);

    size_t base = (size_t)b * TT + (size_t)seg * STEP + (size_t)n1;
    float wn = wmix[iblk + 1];
    float4 dv;
    if (iblk == 0) {
        float4 xv = *(const float4*)(x + base);
        float w0 = wmix[0];
        dv.x = w0 * xv.x + wn * yv.x;
        dv.y = w0 * xv.y + wn * yv.y;
        dv.z = w0 * xv.z + wn * yv.z;
        dv.w = w0 * xv.w + wn * yv.w;
    } else {
        dv = *(const float4*)(dout + base);
        dv.x += wn * yv.x;
        dv.y += wn * yv.y;
        dv.z += wn * yv.z;
        dv.w += wn * yv.w;
    }
    *(float4*)(dout + base) = dv;

    if (do_an) {
        ystage4[tid] = yv;
        __syncthreads();
        int K2 = counts[iblk + 1];
        if (K2 > 0) {
            const float* ys = (const float*)ystage4;
            int lane = tid & 63, w = tid >> 6;
            float xr[16];
#pragma unroll
            for (int i = 0; i < 16; ++i) xr[i] = ys[lane + (i << 6)];
            const int* bl2 = bins + (iblk + 1) * NC;
            float2* Hout = H2 + (size_t)(b * FRM + seg) * K2;
            for (int j = w; j < K2; j += 4) {
                int k = bl2[j];
                float cW, sW; cis_rev(k << 6, &cW, &sW);
                float Wr = cW, Wi = -sW;
                float hr = 0.f, hi = 0.f;
#pragma unroll
                for (int i = 15; i >= 0; --i) {
                    float nr = hr * Wr - hi * Wi + xr[i];
                    hi = hr * Wi + hi * Wr;
                    hr = nr;
                }
                float cb, sb; cis_rev(k * lane, &cb, &sb);
                float re = hr * cb + hi * sb;
                float im = hi * cb - hr * sb;
#pragma unroll
                for (int m = 32; m >= 1; m >>= 1) {
                    re += __shfl_xor(re, m, 64);
                    im += __shfl_xor(im, m, 64);
                }
                if (lane == 0) Hout[j] = make_float2(re, im);
            }
        }
    }
}

extern "C" void kernel_launch(void* const* d_in, const int* in_sizes, int n_in,
                              void* d_out, int out_size, void* d_ws, size_t ws_size,
                              hipStream_t stream)
{
    const float* x         = (const float*)d_in[0];
    const float* transfers = (const float*)d_in[1];
    const float* gains     = (const float*)d_in[2];
    const float* mixer     = (const float*)d_in[3];
    float* dout = (float*)d_out;

    uint8_t* ws = (uint8_t*)d_ws;
    int*   counts = (int*)ws;                          // 16 B
    int*   bins   = (int*)(ws + 64);                   // 4*1025*4 = 16400 B
    float* tvals  = (float*)(ws + 64 + 16400);         // 16400 B
    float* wmix   = (float*)(ws + 64 + 16400 + 16400); // 20 B
    const size_t HDR = 65536;

    // per-k bytes: two ping-pong S buffers (2 * BAT*FRM*8) + NB twiddle rows (NB*1024*8)
    long long perk = 2LL * BAT * FRM * 8 + (long long)NB * 1024 * 8;
    long long km = ((long long)ws_size - (long long)HDR) / perk;
    int kmax = (int)((km < 1) ? 1 : ((km > NC) ? NC : km));
    float2* S0 = (float2*)(ws + HDR);
    float2* S1 = S0 + (size_t)BAT * FRM * kmax;
    float2* TW = S1 + (size_t)BAT * FRM * kmax;        // NB * kmax * 1024 float2

    setup_kernel<<<NB, 1024, 0, stream>>>(transfers, mixer, counts, bins, tvals, wmix, kmax);
    twiddle_kernel<<<NB * 32, 256, 0, stream>>>(counts, bins, TW, kmax);
    analysis_kernel<<<BAT * FRM, 256, 0, stream>>>(x, counts, bins, S0, 0);

    float2* cur = S0;
    float2* nxt = S1;
    for (int i = 0; i < NB; ++i) {
        scan_kernel<<<BAT * 64, 256, 0, stream>>>(cur, counts, bins, tvals, i);
        fused_synth_kernel<<<BAT * FRM, 256, 0, stream>>>(cur, nxt, TW, counts, bins, gains,
                                                          wmix, x, dout, i, (i < NB - 1) ? 1 : 0, kmax);
        float2* t = cur; cur = nxt; nxt = t;
    }
}

// Round 5
// 305.578 us; speedup vs baseline: 2.2445x; 1.0884x over previous
//
#include <hip/hip_runtime.h>
#include <math.h>
#include <stdint.h>

#define NB   4
#define NC   1025
#define WSZ  2048
#define STEP 1024
#define FRM  256
#define BAT  32
#define TT   262144
#define KC   128     // bin chunk held in LDS by the synth kernel

// 1/2048 (exact): phases are integers mod 2048 -> revolutions for v_sin/v_cos
#define RREV (1.0f / 2048.0f)

__device__ __forceinline__ float tanh_fast(float z) {
    float e = __expf(2.0f * z);
    return 1.0f - 2.0f / (e + 1.0f);   // exact tanh identity; inf/0 saturate to +/-1
}

// hardware cis: idx taken mod 2048, argument in revolutions (exact, no range reduction)
__device__ __forceinline__ void cis_rev(int idx, float* c, float* s) {
    float rev = (float)(idx & 2047) * RREV;
    *c = __builtin_amdgcn_cosf(rev);
    *s = __builtin_amdgcn_sinf(rev);
}

// ---------------- setup: compact nonzero bins per block + softmax(mixer) + hann table ----------------
__global__ __launch_bounds__(1024) void setup_kernel(
    const float* __restrict__ transfers, const float* __restrict__ mixer,
    int* __restrict__ counts, int* __restrict__ bins, float* __restrict__ tvals,
    float* __restrict__ wmix, float* __restrict__ hann, int kmax)
{
    int i = blockIdx.x, tid = threadIdx.x;
    __shared__ int wcnt[16], woff[16];
    if (i == 0) {                                   // hann[n] = 0.5 - 0.5 cos(2pi n/2048)
        float cc, ss; cis_rev(tid, &cc, &ss);
        hann[tid] = 0.5f - 0.5f * cc;
    }
    float tv = transfers[i * NC + tid];
    bool nz = (tv != 0.0f);
    unsigned long long mask = __ballot(nz);
    int lane = tid & 63, w = tid >> 6;
    int within = __popcll(mask & ((1ULL << lane) - 1ULL));
    if (lane == 0) wcnt[w] = __popcll(mask);
    __syncthreads();
    if (tid == 0) {
        int acc = 0;
        for (int q = 0; q < 16; ++q) { woff[q] = acc; acc += wcnt[q]; }
        float tvL = transfers[i * NC + 1024];       // tail bin k=1024
        if (tvL != 0.0f && acc < kmax) { bins[i * NC + acc] = 1024; tvals[i * NC + acc] = tvL; acc++; }
        counts[i] = (acc < kmax) ? acc : kmax;
        if (i == 0) {                               // softmax of mixer[5]
            float m = mixer[0];
            for (int q = 1; q < 5; ++q) m = fmaxf(m, mixer[q]);
            float e[5], s = 0.f;
            for (int q = 0; q < 5; ++q) { e[q] = __expf(mixer[q] - m); s += e[q]; }
            for (int q = 0; q < 5; ++q) wmix[q] = e[q] / s;
        }
    }
    __syncthreads();
    if (nz) {
        int pos = woff[w] + within;
        if (pos < kmax) { bins[i * NC + pos] = tid; tvals[i * NC + pos] = tv; }
    }
}

// ---------------- twiddle tables: T[i][j][n] = cis(2pi k_j n / 2048), n in [0,1024) ----------------
__global__ __launch_bounds__(256) void twiddle_kernel(
    const int* __restrict__ counts, const int* __restrict__ bins,
    float2* __restrict__ TW, int kmax)
{
    int i = blockIdx.x >> 5, c = blockIdx.x & 31;
    int K = counts[i];
    for (int j = c; j < K; j += 32) {
        int k = bins[i * NC + j];
        float2* row = TW + ((size_t)i * kmax + j) * 1024;
        for (int n = threadIdx.x; n < 1024; n += 256) {
            float cc, ss; cis_rev(k * n, &cc, &ss);
            row[n] = make_float2(cc, ss);
        }
    }
}

// shared half-frame DFT: xr[16] per lane (n = lane + 64*i), bins j = w, w+4, ... < K,
// twiddles from TW row (TWrow[lane] = cis(+k lane), conj used). 2-bin ILP.
__device__ __forceinline__ void half_dft(
    const float xr[16], int K, const float2* __restrict__ TWb,
    float2* __restrict__ Hout, int lane, int w)
{
    for (int j = w; j < K; j += 8) {
        int j2 = j + 4;
        bool two = (j2 < K);
        const float2* rowA = TWb + ((size_t)j << 10);
        const float2* rowB = two ? (TWb + ((size_t)j2 << 10)) : rowA;
        float2 wA64 = rowA[64], wB64 = rowB[64];
        float2 wAl = rowA[lane], wBl = rowB[lane];
        float WAr = wA64.x, WAi = -wA64.y;
        float WBr = wB64.x, WBi = -wB64.y;
        float hrA = 0.f, hiA = 0.f, hrB = 0.f, hiB = 0.f;
#pragma unroll
        for (int i = 15; i >= 0; --i) {
            float nrA = fmaf(hrA, WAr, fmaf(-hiA, WAi, xr[i]));
            hiA = fmaf(hrA, WAi, hiA * WAr);
            hrA = nrA;
            float nrB = fmaf(hrB, WBr, fmaf(-hiB, WBi, xr[i]));
            hiB = fmaf(hrB, WBi, hiB * WBr);
            hrB = nrB;
        }
        float reA = hrA * wAl.x + hiA * wAl.y;
        float imA = hiA * wAl.x - hrA * wAl.y;
        float reB = hrB * wBl.x + hiB * wBl.y;
        float imB = hiB * wBl.x - hrB * wBl.y;
#pragma unroll
        for (int m = 32; m >= 1; m >>= 1) {
            reA += __shfl_xor(reA, m, 64);
            imA += __shfl_xor(imA, m, 64);
            reB += __shfl_xor(reB, m, 64);
            imB += __shfl_xor(imB, m, 64);
        }
        if (lane == 0) {
            Hout[j] = make_float2(reA, imA);
            if (two) Hout[j2] = make_float2(reB, imB);
        }
    }
}

// ---------------- analysis (block 0 only): sparse DFT of each 1024-sample half-frame ----------------
__global__ __launch_bounds__(256) void analysis_kernel(
    const float* __restrict__ x, const int* __restrict__ counts,
    const float2* __restrict__ TW, float2* __restrict__ H, int iblk, int kmax)
{
    int wg = blockIdx.x;
    int b = wg >> 8, h = wg & 255;
    int tid = threadIdx.x;
    int lane = tid & 63, w = tid >> 6;
    int K = counts[iblk];
    const float* xb = x + (size_t)b * TT + (size_t)h * STEP;
    float xr[16];
#pragma unroll
    for (int i = 0; i < 16; ++i) xr[i] = xb[lane + (i << 6)];
    const float2* TWb = TW + (size_t)iblk * kmax * 1024;
    float2* Hout = H + (size_t)(b * FRM + h) * K;
    half_dft(xr, K, TWb, Hout, lane, w);
}

// ---------------- scan: S_f = H_f + (-1)^k H_{f+1};  O_f = (S_f + O_{f-1}) * t ----------------
// Kogge-Stone over 256 frames; grid = BAT*64 wgs, wg (b, j0) loops bins j = j0, j0+64, ...
__global__ __launch_bounds__(256) void scan_kernel(
    float2* __restrict__ S, const int* __restrict__ counts,
    const int* __restrict__ bins, const float* __restrict__ tvals, int iblk)
{
    int K = counts[iblk];
    int wg = blockIdx.x;
    int b = wg & (BAT - 1), j0 = wg >> 5;
    int f = threadIdx.x;
    __shared__ float shr[FRM], shi[FRM], shg[FRM];
    for (int j = j0; j < K; j += 64) {
        float t = tvals[iblk * NC + j];
        int k = bins[iblk * NC + j];
        float2* Sb = S + (size_t)b * FRM * K + j;
        float2 h1 = Sb[(size_t)f * K];
        float2 h2 = (f < FRM - 1) ? Sb[(size_t)(f + 1) * K] : make_float2(0.f, 0.f);
        float sgn = (k & 1) ? -1.f : 1.f;
        float ar = (h1.x + sgn * h2.x) * t;
        float ai = (h1.y + sgn * h2.y) * t;
        float g = t;
#pragma unroll
        for (int d = 1; d < FRM; d <<= 1) {
            shr[f] = ar; shi[f] = ai; shg[f] = g;
            __syncthreads();
            if (f >= d) {
                ar = fmaf(g, shr[f - d], ar);
                ai = fmaf(g, shi[f - d], ai);
                g *= shg[f - d];
            }
            __syncthreads();
        }
        Sb[(size_t)f * K] = make_float2(ar, ai);
        __syncthreads();
    }
}

// ---------------- fused synthesis + next-block analysis ----------------
// grid = BAT*FRM workgroups of 256; wg (b,seg) produces samples [seg*1024,(seg+1)*1024).
// out[n1] = A + hann[n1]*B, A = sum Re[c2' e^{i2pik n1/2048}], B = sum Re[(c1-c2') e],
// c1 = g*O_{f1}, c2' = g*(-1)^k*O_{f2}; e from the L2-resident table. The 1024 produced
// samples (= half-frame seg of y) are staged through LDS and the next block's half-frame
// DFT is computed in the same workgroup (y never touches HBM).
__global__ __launch_bounds__(256, 6) void fused_synth_kernel(
    const float2* __restrict__ S, float2* __restrict__ H2,
    const float2* __restrict__ TW,
    const int* __restrict__ counts, const int* __restrict__ bins,
    const float* __restrict__ gains, const float* __restrict__ wmix,
    const float* __restrict__ hann, const float* __restrict__ x,
    float* __restrict__ dout, int iblk, int do_an, int kmax)
{
    __shared__ float4 cdat[KC];     // c2r, c2i, c1r-c2r, c1i-c2i
    __shared__ float4 ystage4[256];

    int wg = blockIdx.x;
    int b = wg >> 8, seg = wg & 255;
    int tid = threadIdx.x;
    int n1 = tid << 2;
    size_t base = (size_t)b * TT + (size_t)seg * STEP + (size_t)n1;

    // early prefetch: RMW operand + hann weights (consumed only in the epilogue)
    const float* prevsrc = (iblk == 0) ? x : dout;
    float4 pv = *(const float4*)(prevsrc + base);
    float4 hv = *(const float4*)(hann + n1);
    float wsel = (iblk == 0) ? wmix[0] : 1.0f;
    float wn = wmix[iblk + 1];
    float gain = gains[iblk];

    int K = counts[iblk];
    const int* bl = bins + iblk * NC;
    const float2* Ob = S + (size_t)b * FRM * K;
    const float2* TWb = TW + (size_t)iblk * kmax * 1024;
    int f1 = seg, f2 = seg - 1;

    float accA0 = 0.f, accA1 = 0.f, accA2 = 0.f, accA3 = 0.f;
    float accB0 = 0.f, accB1 = 0.f, accB2 = 0.f, accB3 = 0.f;

    for (int c0 = 0; c0 < K; c0 += KC) {
        int cs = (K - c0 < KC) ? (K - c0) : KC;
        if (tid < cs) {
            int j = c0 + tid;
            int k = bl[j];
            float g = ((k == 0) || (k == 1024)) ? (1.0f / 2048.0f) : (2.0f / 2048.0f);
            float2 o1 = Ob[(size_t)f1 * K + j];
            float c1r = o1.x * g, c1i = o1.y * g;
            float c2r = 0.f, c2i = 0.f;
            if (f2 >= 0) {
                float2 o2 = Ob[(size_t)f2 * K + j];
                float s = (k & 1) ? -g : g;            // fold (-1)^k into second half
                c2r = o2.x * s; c2i = o2.y * s;
            }
            cdat[tid] = make_float4(c2r, c2i, c1r - c2r, c1i - c2i);
        }
        __syncthreads();
        // rows are 512 float4 apart; pointer-increment addressing, x2 unroll for load pipelining
        const float4* tp = (const float4*)TWb + (((size_t)c0) << 9) + (tid << 1);
        int jj = 0;
        for (; jj + 2 <= cs; jj += 2) {
            float4 tA0 = tp[0];
            float4 tB0 = tp[1];
            float4 tA1 = tp[512];
            float4 tB1 = tp[513];
            tp += 1024;
            float4 cd0 = cdat[jj];
            float4 cd1 = cdat[jj + 1];
            accA0 = fmaf(cd0.x, tA0.x, accA0); accA0 = fmaf(-cd0.y, tA0.y, accA0);
            accB0 = fmaf(cd0.z, tA0.x, accB0); accB0 = fmaf(-cd0.w, tA0.y, accB0);
            accA1 = fmaf(cd0.x, tA0.z, accA1); accA1 = fmaf(-cd0.y, tA0.w, accA1);
            accB1 = fmaf(cd0.z, tA0.z, accB1); accB1 = fmaf(-cd0.w, tA0.w, accB1);
            accA2 = fmaf(cd0.x, tB0.x, accA2); accA2 = fmaf(-cd0.y, tB0.y, accA2);
            accB2 = fmaf(cd0.z, tB0.x, accB2); accB2 = fmaf(-cd0.w, tB0.y, accB2);
            accA3 = fmaf(cd0.x, tB0.z, accA3); accA3 = fmaf(-cd0.y, tB0.w, accA3);
            accB3 = fmaf(cd0.z, tB0.z, accB3); accB3 = fmaf(-cd0.w, tB0.w, accB3);
            accA0 = fmaf(cd1.x, tA1.x, accA0); accA0 = fmaf(-cd1.y, tA1.y, accA0);
            accB0 = fmaf(cd1.z, tA1.x, accB0); accB0 = fmaf(-cd1.w, tA1.y, accB0);
            accA1 = fmaf(cd1.x, tA1.z, accA1); accA1 = fmaf(-cd1.y, tA1.w, accA1);
            accB1 = fmaf(cd1.z, tA1.z, accB1); accB1 = fmaf(-cd1.w, tA1.w, accB1);
            accA2 = fmaf(cd1.x, tB1.x, accA2); accA2 = fmaf(-cd1.y, tB1.y, accA2);
            accB2 = fmaf(cd1.z, tB1.x, accB2); accB2 = fmaf(-cd1.w, tB1.y, accB2);
            accA3 = fmaf(cd1.x, tB1.z, accA3); accA3 = fmaf(-cd1.y, tB1.w, accA3);
            accB3 = fmaf(cd1.z, tB1.z, accB3); accB3 = fmaf(-cd1.w, tB1.w, accB3);
        }
        if (jj < cs) {
            float4 tA = tp[0];
            float4 tB = tp[1];
            float4 cd = cdat[jj];
            accA0 = fmaf(cd.x, tA.x, accA0); accA0 = fmaf(-cd.y, tA.y, accA0);
            accB0 = fmaf(cd.z, tA.x, accB0); accB0 = fmaf(-cd.w, tA.y, accB0);
            accA1 = fmaf(cd.x, tA.z, accA1); accA1 = fmaf(-cd.y, tA.w, accA1);
            accB1 = fmaf(cd.z, tA.z, accB1); accB1 = fmaf(-cd.w, tA.w, accB1);
            accA2 = fmaf(cd.x, tB.x, accA2); accA2 = fmaf(-cd.y, tB.y, accA2);
            accB2 = fmaf(cd.z, tB.x, accB2); accB2 = fmaf(-cd.w, tB.y, accB2);
            accA3 = fmaf(cd.x, tB.z, accA3); accA3 = fmaf(-cd.y, tB.w, accA3);
            accB3 = fmaf(cd.z, tB.z, accB3); accB3 = fmaf(-cd.w, tB.w, accB3);
        }
        __syncthreads();
    }

    float4 yv;
    yv.x = tanh_fast(fmaf(hv.x, accB0, accA0) * gain);
    yv.y = tanh_fast(fmaf(hv.y, accB1, accA1) * gain);
    yv.z = tanh_fast(fmaf(hv.z, accB2, accA2) * gain);
    yv.w = tanh_fast(fmaf(hv.w, accB3, accA3) * gain);

    float4 dv;
    dv.x = fmaf(wsel, pv.x, wn * yv.x);
    dv.y = fmaf(wsel, pv.y, wn * yv.y);
    dv.z = fmaf(wsel, pv.z, wn * yv.z);
    dv.w = fmaf(wsel, pv.w, wn * yv.w);
    *(float4*)(dout + base) = dv;

    if (do_an) {
        ystage4[tid] = yv;
        __syncthreads();
        int K2 = counts[iblk + 1];
        if (K2 > 0) {
            const float* ys = (const float*)ystage4;
            int lane = tid & 63, w = tid >> 6;
            float xr[16];
#pragma unroll
            for (int i = 0; i < 16; ++i) xr[i] = ys[lane + (i << 6)];
            const float2* TW2b = TW + (size_t)(iblk + 1) * kmax * 1024;
            float2* Hout = H2 + (size_t)(b * FRM + seg) * K2;
            half_dft(xr, K2, TW2b, Hout, lane, w);
        }
    }
}

extern "C" void kernel_launch(void* const* d_in, const int* in_sizes, int n_in,
                              void* d_out, int out_size, void* d_ws, size_t ws_size,
                              hipStream_t stream)
{
    const float* x         = (const float*)d_in[0];
    const float* transfers = (const float*)d_in[1];
    const float* gains     = (const float*)d_in[2];
    const float* mixer     = (const float*)d_in[3];
    float* dout = (float*)d_out;

    uint8_t* ws = (uint8_t*)d_ws;
    int*   counts = (int*)ws;                          // 16 B
    int*   bins   = (int*)(ws + 64);                   // 4*1025*4 = 16400 B
    float* tvals  = (float*)(ws + 64 + 16400);         // 16400 B
    float* wmix   = (float*)(ws + 64 + 16400 + 16400); // 20 B
    float* hann   = (float*)(ws + 36864);              // 1024 floats
    const size_t HDR = 65536;

    // per-k bytes: two ping-pong S buffers (2 * BAT*FRM*8) + NB twiddle rows (NB*1024*8)
    long long perk = 2LL * BAT * FRM * 8 + (long long)NB * 1024 * 8;
    long long km = ((long long)ws_size - (long long)HDR) / perk;
    int kmax = (int)((km < 1) ? 1 : ((km > NC) ? NC : km));
    float2* S0 = (float2*)(ws + HDR);
    float2* S1 = S0 + (size_t)BAT * FRM * kmax;
    float2* TW = S1 + (size_t)BAT * FRM * kmax;        // NB * kmax * 1024 float2

    setup_kernel<<<NB, 1024, 0, stream>>>(transfers, mixer, counts, bins, tvals, wmix, hann, kmax);
    twiddle_kernel<<<NB * 32, 256, 0, stream>>>(counts, bins, TW, kmax);
    analysis_kernel<<<BAT * FRM, 256, 0, stream>>>(x, counts, TW, S0, 0, kmax);

    float2* cur = S0;
    float2* nxt = S1;
    for (int i = 0; i < NB; ++i) {
        scan_kernel<<<BAT * 64, 256, 0, stream>>>(cur, counts, bins, tvals, i);
        fused_synth_kernel<<<BAT * FRM, 256, 0, stream>>>(cur, nxt, TW, counts, bins, gains,
                                                          wmix, hann, x, dout, i,
                                                          (i < NB - 1) ? 1 : 0, kmax);
        float2* t = cur; cur = nxt; nxt = t;
    }
}